// Round 4
// baseline (1213.217 us; speedup 1.0000x reference)
//
#include <hip/hip_runtime.h>
#include <math.h>

#define N_ENT  150000
#define N_USR  60000
#define CDIM   64
#define NE     1000000
#define NNZV   1000000
#define NREL9  9                        // weight rows incl. np-wrap row 8
#define NTOT   (2 * N_ENT + N_USR)      // 360000 concatenated segment counters
#define TOTAL_ITEMS (NE + 2 * NNZV)     // 3000000 (scan sentinel)
#define SCAN_B ((NTOT + 1023) / 1024)   // 352 scan blocks

// Full 64-lane wave sum (all lanes get the result).
__device__ __forceinline__ float wave_sum(float v) {
#pragma unroll
    for (int m = 32; m > 0; m >>= 1) v += __shfl_xor(v, m, 64);
    return v;
}

// Block-wide exclusive scan (blockDim multiple of 64, <=1024). lds: >=16 ints.
__device__ __forceinline__ int block_excl_scan(int v, int* lds) {
    int lane = threadIdx.x & 63, wid = threadIdx.x >> 6;
    int incl = v;
#pragma unroll
    for (int o = 1; o < 64; o <<= 1) {
        int t = __shfl_up(incl, o, 64);
        if (lane >= o) incl += t;
    }
    if (lane == 63) lds[wid] = incl;
    __syncthreads();
    int nw = blockDim.x >> 6;
    if ((int)threadIdx.x < nw) {
        int s = lds[threadIdx.x];
        int si = s;
        for (int o = 1; o < nw; o <<= 1) {
            int t = __shfl_up(si, o, 64);
            if ((int)threadIdx.x >= o) si += t;
        }
        lds[threadIdx.x] = si - s;  // exclusive offset for this wave
    }
    __syncthreads();
    return incl - v + lds[wid];
}

__global__ __launch_bounds__(256) void k_zero(int* __restrict__ p, int n) {
    int i = blockIdx.x * 256 + threadIdx.x;
    if (i < n) p[i] = 0;
}

// ---- CSR build: histogram -> scan(start,cursor) -> scatter(cursor only) ----

__global__ __launch_bounds__(256) void k_hist(
    const int* __restrict__ head, const int* __restrict__ cols,
    const int* __restrict__ rows, int* __restrict__ cnt)
{
    int i = blockIdx.x * 256 + threadIdx.x;
    if (i >= NE) return;
    atomicAdd(cnt + head[i], 1);
    atomicAdd(cnt + N_ENT + cols[i], 1);
    atomicAdd(cnt + 2 * N_ENT + rows[i], 1);
}

__global__ __launch_bounds__(1024) void k_bsum(
    const int* __restrict__ cnt, int* __restrict__ bsum)
{
    __shared__ int lds[16];
    int i = blockIdx.x * 1024 + threadIdx.x;
    int v = (i < NTOT) ? cnt[i] : 0;
#pragma unroll
    for (int m = 32; m > 0; m >>= 1) v += __shfl_xor(v, m, 64);
    int lane = threadIdx.x & 63, wid = threadIdx.x >> 6;
    if (lane == 0) lds[wid] = v;
    __syncthreads();
    if (threadIdx.x == 0) {
        int s = 0;
        for (int k = 0; k < 16; ++k) s += lds[k];
        bsum[blockIdx.x] = s;
    }
}

__global__ __launch_bounds__(512) void k_scan_small(int* __restrict__ bsum)
{
    __shared__ int lds[16];
    int i = threadIdx.x;
    int v = (i < SCAN_B) ? bsum[i] : 0;
    int e = block_excl_scan(v, lds);
    if (i < SCAN_B) bsum[i] = e;
}

// start[i] = exclusive prefix (immutable afterwards); start[NTOT] = sentinel.
// cursor[i] = same value; ONLY cursor is mutated by k_scatter.
__global__ __launch_bounds__(1024) void k_scan_apply(
    const int* __restrict__ cnt, const int* __restrict__ bsum,
    int* __restrict__ start, int* __restrict__ cursor)
{
    __shared__ int lds[16];
    int i = blockIdx.x * 1024 + threadIdx.x;
    int v = (i < NTOT) ? cnt[i] : 0;
    int e = block_excl_scan(v, lds) + bsum[blockIdx.x];
    if (i < NTOT) { start[i] = e; cursor[i] = e; }
    else if (i == NTOT) { start[i] = TOTAL_ITEMS; }
}

// Scatter payloads into segment-sorted arrays. Mutates cursor only.
__global__ __launch_bounds__(256) void k_scatter(
    const int* __restrict__ head, const int* __restrict__ tail,
    const int* __restrict__ etype,
    const int* __restrict__ rows, const int* __restrict__ cols,
    const float* __restrict__ vals,
    int* __restrict__ cursor,
    int* __restrict__ pk_h,                              // tail | rt<<18, by head
    int* __restrict__ row_c, float* __restrict__ val_c,  // by col
    int* __restrict__ col_r, float* __restrict__ val_r)  // by row
{
    int i = blockIdx.x * 256 + threadIdx.x;
    if (i >= NE) return;
    int rt = etype[i] - 1;
    if (rt < 0) rt = 8;                                  // weight[-1] -> row 8
    int p = atomicAdd(cursor + head[i], 1);
    if ((unsigned)p < (unsigned)NE) pk_h[p] = tail[i] | (rt << 18);
    int r = rows[i], c = cols[i];
    float v = vals[i];
    p = atomicAdd(cursor + N_ENT + c, 1) - NE;
    if ((unsigned)p < (unsigned)NNZV) { row_c[p] = r; val_c[p] = v; }
    p = atomicAdd(cursor + 2 * N_ENT + r, 1) - 2 * NE;
    if ((unsigned)p < (unsigned)NNZV) { col_r[p] = c; val_r[p] = v; }
}

// ---- Per-hop phase 1: sq[e][rt] = sum_c ent[e][c]^2 * wt[rt][c]^2 --------
// One wave per entity; 9 wave_sums.
__global__ __launch_bounds__(256) void k_sqnorm(
    const float* __restrict__ ent_cur, const float* __restrict__ wt,
    float* __restrict__ sq)
{
    int e = (blockIdx.x * 256 + threadIdx.x) >> 6;
    int lane = threadIdx.x & 63;
    if (e >= N_ENT) return;
    float own = ent_cur[(size_t)e * CDIM + lane];
    float o2 = own * own;
    float mine = 0.f;
#pragma unroll
    for (int rt = 0; rt < NREL9; ++rt) {
        float r = wt[rt * CDIM + lane];
        float s = wave_sum(o2 * r * r);
        if (lane == rt) mine = s;
    }
    if (lane < NREL9) sq[(size_t)e * NREL9 + lane] = mine;
}

// ---- Per-hop phase 2: scalar per-segment softmax -------------------------
// One THREAD per entity: att_j = sq[h][rt]*sq[t][rt]; w[j]=exp(att-m);
// inv_l[e] = 1/sum. All scalar; no per-channel work.
__global__ __launch_bounds__(256) void k_edge_w(
    const int* __restrict__ start, const int* __restrict__ pk_h,
    const float* __restrict__ sq,
    float* __restrict__ w, float* __restrict__ inv_l)
{
    int e = blockIdx.x * 256 + threadIdx.x;
    if (e >= N_ENT) return;
    int s1 = min(start[e + 1], NE);
    int s0 = min(start[e], s1);
    float sqh[NREL9];
#pragma unroll
    for (int r = 0; r < NREL9; ++r) sqh[r] = sq[(size_t)e * NREL9 + r];
    float m = 0.f;                       // att >= 0
    for (int j = s0; j < s1; ++j) {
        int pk = pk_h[j];
        int t = pk & 0x3FFFF, rt = (pk >> 18) & 15;
        float a = sqh[rt] * sq[(size_t)t * NREL9 + rt];
        w[j] = a;
        m = fmaxf(m, a);
    }
    float l = 0.f;
    for (int j = s0; j < s1; ++j) {
        float p = __expf(w[j] - m);
        w[j] = p;
        l += p;
    }
    inv_l[e] = (l > 0.f) ? 1.f / l : 0.f;
}

// ---- Per-hop phase 3: vector gather + normalize + residual ---------------
// One wave per entity. FIRST: out = own + y; else out += y.
template <bool FIRST, bool LAST>
__global__ __launch_bounds__(256) void k_entity(
    const float* __restrict__ ent_cur, const float* __restrict__ usr_cur,
    const float* __restrict__ wt, const int* __restrict__ start,
    const int* __restrict__ pk_h, const float* __restrict__ w,
    const float* __restrict__ inv_l,
    const int* __restrict__ row_c, const float* __restrict__ val_c,
    float* __restrict__ ent_next, float* __restrict__ out_ent)
{
    int e = (blockIdx.x * 256 + threadIdx.x) >> 6;
    int lane = threadIdx.x & 63;
    if (e >= N_ENT) return;

    // softmax-weighted neighbor aggregation (weights precomputed)
    int s1 = min(start[e + 1], NE);
    int s0 = min(start[e], s1);
    float acc = 0.f;
    for (int j = s0; j < s1; ++j) {
        int pk = pk_h[j];
        float wj = w[j];
        int t = pk & 0x3FFFF, rt = (pk >> 18) & 15;
        acc += wj * ent_cur[(size_t)t * CDIM + lane] * wt[rt * CDIM + lane];
    }
    float agg = acc * inv_l[e];

    // + interact_mat^T @ user_emb  (nnz with col == e)
    int c1 = min(start[N_ENT + e + 1] - NE, NNZV);
    int c0 = max(min(start[N_ENT + e] - NE, c1), 0);
    for (int j = c0; j < c1; ++j) {
        int u = row_c[j];
        agg += val_c[j] * usr_cur[(size_t)u * CDIM + lane];
    }

    float s = wave_sum(agg * agg);
    float y = agg / fmaxf(sqrtf(s), 1e-12f);
    if (!LAST) ent_next[(size_t)e * CDIM + lane] = y;
    size_t oi = (size_t)e * CDIM + lane;
    float own = ent_cur[oi];
    if (FIRST) out_ent[oi] = own + y;
    else       out_ent[oi] += y;
}

// One wave per user: user_agg = sum val*ent[col]; normalize; residual.
template <bool FIRST, bool LAST>
__global__ __launch_bounds__(256) void k_user(
    const float* __restrict__ ent_cur, const float* __restrict__ usr_base,
    const int* __restrict__ start,
    const int* __restrict__ col_r, const float* __restrict__ val_r,
    float* __restrict__ usr_next, float* __restrict__ out_usr)
{
    int u = (blockIdx.x * 256 + threadIdx.x) >> 6;
    int lane = threadIdx.x & 63;
    if (u >= N_USR) return;
    int s1 = min(start[2 * N_ENT + u + 1] - 2 * NE, NNZV);
    int s0 = max(min(start[2 * N_ENT + u] - 2 * NE, s1), 0);
    float acc = 0.f;
    for (int j = s0; j < s1; ++j) {
        int c = col_r[j];
        acc += val_r[j] * ent_cur[(size_t)c * CDIM + lane];
    }
    float s = wave_sum(acc * acc);
    float y = acc / fmaxf(sqrtf(s), 1e-12f);
    if (!LAST) usr_next[(size_t)u * CDIM + lane] = y;
    size_t oi = (size_t)u * CDIM + lane;
    if (FIRST) out_usr[oi] = usr_base[oi] + y;
    else       out_usr[oi] += y;
}

extern "C" void kernel_launch(void* const* d_in, const int* in_sizes, int n_in,
                              void* d_out, int out_size, void* d_ws, size_t ws_size,
                              hipStream_t stream)
{
    const float* user_emb   = (const float*)d_in[0];
    const float* entity_emb = (const float*)d_in[1];
    const float* wt         = (const float*)d_in[2];
    const float* inter_vals = (const float*)d_in[3];
    const int*   edge_index = (const int*)d_in[4];
    const int*   etype      = (const int*)d_in[5];
    const int*   inter_rows = (const int*)d_in[6];
    const int*   inter_cols = (const int*)d_in[7];
    const int* head  = edge_index;
    const int* tailp = edge_index + NE;

    // Workspace layout (~90 MB); every buffer written before read each call.
    float* ent_a  = (float*)d_ws;                          // N_ENT*64
    float* usr_a  = ent_a + (size_t)N_ENT * CDIM;          // N_USR*64
    int*   cnt    = (int*)(usr_a + (size_t)N_USR * CDIM);  // NTOT
    int*   start  = cnt + NTOT;                            // NTOT+1
    int*   cursor = start + NTOT + 1;                      // NTOT+1
    int*   pk_h   = cursor + NTOT + 1;                     // NE
    int*   row_c  = pk_h + NE;                             // NNZ
    float* val_c  = (float*)(row_c + NNZV);                // NNZ
    int*   col_r  = (int*)(val_c + NNZV);                  // NNZ
    float* val_r  = (float*)(col_r + NNZV);                // NNZ
    int*   bsum   = (int*)(val_r + NNZV);                  // SCAN_B
    float* sq     = (float*)(bsum + SCAN_B);               // N_ENT*9
    float* w_e    = sq + (size_t)N_ENT * NREL9;            // NE
    float* inv_l  = w_e + NE;                              // N_ENT

    float* out_ent = (float*)d_out;
    float* out_usr = out_ent + (size_t)N_ENT * CDIM;

    // ---- CSR build (indices are hop-invariant: once per call) ----
    k_zero<<<(NTOT + 255) / 256, 256, 0, stream>>>(cnt, NTOT);
    k_hist<<<(NE + 255) / 256, 256, 0, stream>>>(head, inter_cols, inter_rows, cnt);
    k_bsum<<<SCAN_B, 1024, 0, stream>>>(cnt, bsum);
    k_scan_small<<<1, 512, 0, stream>>>(bsum);
    k_scan_apply<<<SCAN_B, 1024, 0, stream>>>(cnt, bsum, start, cursor);
    k_scatter<<<(NE + 255) / 256, 256, 0, stream>>>(
        head, tailp, etype, inter_rows, inter_cols, inter_vals,
        cursor, pk_h, row_c, val_c, col_r, val_r);

    const int EG = N_ENT / 4;   // 4 waves per 256-thread block, exact
    const int UG = N_USR / 4;
    const int EG1 = (N_ENT + 255) / 256;

    // ---- hop 1: read inputs, write ent_a/usr_a, out = input + y1 ----
    k_sqnorm<<<EG, 256, 0, stream>>>(entity_emb, wt, sq);
    k_edge_w<<<EG1, 256, 0, stream>>>(start, pk_h, sq, w_e, inv_l);
    k_user<true, false><<<UG, 256, 0, stream>>>(
        entity_emb, user_emb, start, col_r, val_r, usr_a, out_usr);
    k_entity<true, false><<<EG, 256, 0, stream>>>(
        entity_emb, user_emb, wt, start, pk_h, w_e, inv_l,
        row_c, val_c, ent_a, out_ent);

    // ---- hop 2: read ent_a/usr_a, out += y2 (no next buffers) ----
    k_sqnorm<<<EG, 256, 0, stream>>>(ent_a, wt, sq);
    k_edge_w<<<EG1, 256, 0, stream>>>(start, pk_h, sq, w_e, inv_l);
    k_user<false, true><<<UG, 256, 0, stream>>>(
        ent_a, nullptr, start, col_r, val_r, nullptr, out_usr);
    k_entity<false, true><<<EG, 256, 0, stream>>>(
        ent_a, usr_a, wt, start, pk_h, w_e, inv_l,
        row_c, val_c, nullptr, out_ent);
}

// Round 5
// 821.526 us; speedup vs baseline: 1.4768x; 1.4768x over previous
//
#include <hip/hip_runtime.h>
#include <math.h>

#define N_ENT  150000
#define N_USR  60000
#define CDIM   64
#define NE     1000000
#define NNZV   1000000
#define NREL9  9                        // weight rows incl. np-wrap row 8
#define NTOT   (2 * N_ENT + N_USR)      // 360000 concatenated segment counters
#define TOTAL_ITEMS (NE + 2 * NNZV)     // 3000000 (scan sentinel)
#define SCAN_B ((NTOT + 1023) / 1024)   // 352 scan blocks

// Full 64-lane wave sum (all lanes get the result).
__device__ __forceinline__ float wave_sum(float v) {
#pragma unroll
    for (int m = 32; m > 0; m >>= 1) v += __shfl_xor(v, m, 64);
    return v;
}

__device__ __forceinline__ float wave_max(float v) {
#pragma unroll
    for (int m = 32; m > 0; m >>= 1) v = fmaxf(v, __shfl_xor(v, m, 64));
    return v;
}

// Block-wide exclusive scan (blockDim multiple of 64, <=1024). lds: >=16 ints.
__device__ __forceinline__ int block_excl_scan(int v, int* lds) {
    int lane = threadIdx.x & 63, wid = threadIdx.x >> 6;
    int incl = v;
#pragma unroll
    for (int o = 1; o < 64; o <<= 1) {
        int t = __shfl_up(incl, o, 64);
        if (lane >= o) incl += t;
    }
    if (lane == 63) lds[wid] = incl;
    __syncthreads();
    int nw = blockDim.x >> 6;
    if ((int)threadIdx.x < nw) {
        int s = lds[threadIdx.x];
        int si = s;
        for (int o = 1; o < nw; o <<= 1) {
            int t = __shfl_up(si, o, 64);
            if ((int)threadIdx.x >= o) si += t;
        }
        lds[threadIdx.x] = si - s;  // exclusive offset for this wave
    }
    __syncthreads();
    return incl - v + lds[wid];
}

__global__ __launch_bounds__(256) void k_zero(int* __restrict__ p, int n) {
    int i = blockIdx.x * 256 + threadIdx.x;
    if (i < n) p[i] = 0;
}

// ---- CSR build: histogram -> scan(start,cursor) -> scatter(cursor only) ----

__global__ __launch_bounds__(256) void k_hist(
    const int* __restrict__ head, const int* __restrict__ cols,
    const int* __restrict__ rows, int* __restrict__ cnt)
{
    int i = blockIdx.x * 256 + threadIdx.x;
    if (i >= NE) return;
    atomicAdd(cnt + head[i], 1);
    atomicAdd(cnt + N_ENT + cols[i], 1);
    atomicAdd(cnt + 2 * N_ENT + rows[i], 1);
}

__global__ __launch_bounds__(1024) void k_bsum(
    const int* __restrict__ cnt, int* __restrict__ bsum)
{
    __shared__ int lds[16];
    int i = blockIdx.x * 1024 + threadIdx.x;
    int v = (i < NTOT) ? cnt[i] : 0;
#pragma unroll
    for (int m = 32; m > 0; m >>= 1) v += __shfl_xor(v, m, 64);
    int lane = threadIdx.x & 63, wid = threadIdx.x >> 6;
    if (lane == 0) lds[wid] = v;
    __syncthreads();
    if (threadIdx.x == 0) {
        int s = 0;
        for (int k = 0; k < 16; ++k) s += lds[k];
        bsum[blockIdx.x] = s;
    }
}

__global__ __launch_bounds__(512) void k_scan_small(int* __restrict__ bsum)
{
    __shared__ int lds[16];
    int i = threadIdx.x;
    int v = (i < SCAN_B) ? bsum[i] : 0;
    int e = block_excl_scan(v, lds);
    if (i < SCAN_B) bsum[i] = e;
}

// start[i] = exclusive prefix (immutable afterwards); start[NTOT] = sentinel.
// cursor[i] = same value; ONLY cursor is mutated by k_scatter.
__global__ __launch_bounds__(1024) void k_scan_apply(
    const int* __restrict__ cnt, const int* __restrict__ bsum,
    int* __restrict__ start, int* __restrict__ cursor)
{
    __shared__ int lds[16];
    int i = blockIdx.x * 1024 + threadIdx.x;
    int v = (i < NTOT) ? cnt[i] : 0;
    int e = block_excl_scan(v, lds) + bsum[blockIdx.x];
    if (i < NTOT) { start[i] = e; cursor[i] = e; }
    else if (i == NTOT) { start[i] = TOTAL_ITEMS; }
}

// Scatter payloads into segment-sorted arrays. Mutates cursor only.
__global__ __launch_bounds__(256) void k_scatter(
    const int* __restrict__ head, const int* __restrict__ tail,
    const int* __restrict__ etype,
    const int* __restrict__ rows, const int* __restrict__ cols,
    const float* __restrict__ vals,
    int* __restrict__ cursor,
    int* __restrict__ pk_h,                  // tail | rt<<18, sorted by head
    int2* __restrict__ rc,                   // (row, valbits) sorted by col
    int2* __restrict__ cv)                   // (col, valbits) sorted by row
{
    int i = blockIdx.x * 256 + threadIdx.x;
    if (i >= NE) return;
    int rt = etype[i] - 1;
    if (rt < 0) rt = 8;                      // weight[-1] -> row 8 (np wrap)
    int p = atomicAdd(cursor + head[i], 1);
    if ((unsigned)p < (unsigned)NE) pk_h[p] = tail[i] | (rt << 18);
    int r = rows[i], c = cols[i];
    int vb = __float_as_int(vals[i]);
    p = atomicAdd(cursor + N_ENT + c, 1) - NE;
    if ((unsigned)p < (unsigned)NNZV) rc[p] = make_int2(r, vb);
    p = atomicAdd(cursor + 2 * N_ENT + r, 1) - 2 * NE;
    if ((unsigned)p < (unsigned)NNZV) cv[p] = make_int2(c, vb);
}

// ---- sq[e][rt] = sum_c ent[e][c]^2 * wt[rt][c]^2 (hop-1 input only) ------
__global__ __launch_bounds__(256) void k_sqnorm(
    const float* __restrict__ ent_cur, const float* __restrict__ wt,
    float* __restrict__ sq)
{
    int e = (blockIdx.x * 256 + threadIdx.x) >> 6;
    int lane = threadIdx.x & 63;
    if (e >= N_ENT) return;
    float own = ent_cur[(e << 6) + lane];
    float o2 = own * own;
    float mine = 0.f;
#pragma unroll
    for (int rt = 0; rt < NREL9; ++rt) {
        float r = wt[(rt << 6) + lane];
        float s = wave_sum(o2 * r * r);
        if (lane == rt) mine = s;
    }
    if (lane < NREL9) sq[e * NREL9 + lane] = mine;
}

// ---- Fused per-entity kernel: wave-cooperative softmax + MLP'd gathers ---
// One wave per entity. FIRST: out = own + y; else out += y.
// !LAST: writes ent_next AND sq_out (next hop's sq table) from registers.
template <bool FIRST, bool LAST>
__global__ __launch_bounds__(256) void k_entity(
    const float* __restrict__ ent_cur, const float* __restrict__ usr_cur,
    const float* __restrict__ wt, const int* __restrict__ start,
    const int* __restrict__ pk_h, const float* __restrict__ sq_in,
    const int2* __restrict__ rc,
    float* __restrict__ ent_next, float* __restrict__ sq_out,
    float* __restrict__ out_ent)
{
    int e = (blockIdx.x * 256 + threadIdx.x) >> 6;
    int lane = threadIdx.x & 63;
    if (e >= N_ENT) return;

    // --- softmax-weighted neighbor aggregation over edges with head == e ---
    int s1 = min(start[e + 1], NE);
    int s0 = min(start[e], s1);
    float m = 0.f, l = 0.f, acc = 0.f;    // att >= 0 so m=0 init is exact
    for (int base = s0; base < s1; base += 64) {
        int j = base + lane;
        int cnt = min(64, s1 - base);
        int pk = 0; float att = 0.f;
        if (j < s1) {                      // coalesced descriptor load
            pk = pk_h[j];
            int t = pk & 0x3FFFF, rt = (pk >> 18) & 15;
            att = sq_in[e * NREL9 + rt] * sq_in[t * NREL9 + rt];
        }
        float mn = fmaxf(m, wave_max(att));
        float scale = __expf(m - mn);      // first chunk multiplies zeros
        float p = (j < s1) ? __expf(att - mn) : 0.f;
        l = l * scale + wave_sum(p);
        acc *= scale;
        m = mn;
        int k = 0;
        for (; k + 4 <= cnt; k += 4) {     // 4 independent gathers in flight
#pragma unroll
            for (int q = 0; q < 4; ++q) {
                int pkk = __shfl(pk, k + q, 64);
                float wk = __shfl(p, k + q, 64);
                int t = pkk & 0x3FFFF, rt = (pkk >> 18) & 15;
                acc += wk * ent_cur[(t << 6) + lane] * wt[(rt << 6) + lane];
            }
        }
        for (; k < cnt; ++k) {
            int pkk = __shfl(pk, k, 64);
            float wk = __shfl(p, k, 64);
            int t = pkk & 0x3FFFF, rt = (pkk >> 18) & 15;
            acc += wk * ent_cur[(t << 6) + lane] * wt[(rt << 6) + lane];
        }
    }
    float agg = (l > 0.f) ? acc / l : 0.f;

    // --- + interact_mat^T @ user_emb  (nnz with col == e) ---
    int c1 = min(start[N_ENT + e + 1] - NE, NNZV);
    int c0 = max(min(start[N_ENT + e] - NE, c1), 0);
    for (int base = c0; base < c1; base += 64) {
        int j = base + lane;
        int cnt = min(64, c1 - base);
        int rr = 0; float vv = 0.f;
        if (j < c1) { int2 q = rc[j]; rr = q.x; vv = __int_as_float(q.y); }
        int k = 0;
        for (; k + 4 <= cnt; k += 4) {
#pragma unroll
            for (int q = 0; q < 4; ++q) {
                int u = __shfl(rr, k + q, 64);
                float v = __shfl(vv, k + q, 64);
                agg += v * usr_cur[(u << 6) + lane];
            }
        }
        for (; k < cnt; ++k) {
            int u = __shfl(rr, k, 64);
            float v = __shfl(vv, k, 64);
            agg += v * usr_cur[(u << 6) + lane];
        }
    }

    // --- normalize + residual (+ next-hop sq from registers) ---
    float s = wave_sum(agg * agg);
    float y = agg / fmaxf(sqrtf(s), 1e-12f);
    int oi = (e << 6) + lane;
    if (!LAST) {
        ent_next[oi] = y;
        float y2 = y * y;
        float mine = 0.f;
#pragma unroll
        for (int rt = 0; rt < NREL9; ++rt) {
            float r = wt[(rt << 6) + lane];
            float sv = wave_sum(y2 * r * r);
            if (lane == rt) mine = sv;
        }
        if (lane < NREL9) sq_out[e * NREL9 + lane] = mine;
    }
    if (FIRST) out_ent[oi] = ent_cur[oi] + y;
    else       out_ent[oi] += y;
}

// One wave per user: user_agg = sum val*ent[col]; normalize; residual.
template <bool FIRST, bool LAST>
__global__ __launch_bounds__(256) void k_user(
    const float* __restrict__ ent_cur, const float* __restrict__ usr_base,
    const int* __restrict__ start, const int2* __restrict__ cv,
    float* __restrict__ usr_next, float* __restrict__ out_usr)
{
    int u = (blockIdx.x * 256 + threadIdx.x) >> 6;
    int lane = threadIdx.x & 63;
    if (u >= N_USR) return;
    int s1 = min(start[2 * N_ENT + u + 1] - 2 * NE, NNZV);
    int s0 = max(min(start[2 * N_ENT + u] - 2 * NE, s1), 0);
    float acc = 0.f;
    for (int base = s0; base < s1; base += 64) {
        int j = base + lane;
        int cnt = min(64, s1 - base);
        int cc = 0; float vv = 0.f;
        if (j < s1) { int2 q = cv[j]; cc = q.x; vv = __int_as_float(q.y); }
        int k = 0;
        for (; k + 4 <= cnt; k += 4) {
#pragma unroll
            for (int q = 0; q < 4; ++q) {
                int c = __shfl(cc, k + q, 64);
                float v = __shfl(vv, k + q, 64);
                acc += v * ent_cur[(c << 6) + lane];
            }
        }
        for (; k < cnt; ++k) {
            int c = __shfl(cc, k, 64);
            float v = __shfl(vv, k, 64);
            acc += v * ent_cur[(c << 6) + lane];
        }
    }
    float s = wave_sum(acc * acc);
    float y = acc / fmaxf(sqrtf(s), 1e-12f);
    int oi = (u << 6) + lane;
    if (!LAST) usr_next[oi] = y;
    if (FIRST) out_usr[oi] = usr_base[oi] + y;
    else       out_usr[oi] += y;
}

extern "C" void kernel_launch(void* const* d_in, const int* in_sizes, int n_in,
                              void* d_out, int out_size, void* d_ws, size_t ws_size,
                              hipStream_t stream)
{
    const float* user_emb   = (const float*)d_in[0];
    const float* entity_emb = (const float*)d_in[1];
    const float* wt         = (const float*)d_in[2];
    const float* inter_vals = (const float*)d_in[3];
    const int*   edge_index = (const int*)d_in[4];
    const int*   etype      = (const int*)d_in[5];
    const int*   inter_rows = (const int*)d_in[6];
    const int*   inter_cols = (const int*)d_in[7];
    const int* head  = edge_index;
    const int* tailp = edge_index + NE;

    // Workspace layout (~89 MB); every buffer written before read each call.
    float* ent_a  = (float*)d_ws;                          // N_ENT*64
    float* usr_a  = ent_a + (size_t)N_ENT * CDIM;          // N_USR*64
    int2*  rc     = (int2*)(usr_a + (size_t)N_USR * CDIM); // NNZ (8B aligned)
    int2*  cv     = rc + NNZV;                             // NNZ
    int*   pk_h   = (int*)(cv + NNZV);                     // NE
    int*   cnt    = pk_h + NE;                             // NTOT
    int*   start  = cnt + NTOT;                            // NTOT+1
    int*   cursor = start + NTOT + 1;                      // NTOT+1
    int*   bsum   = cursor + NTOT + 1;                     // SCAN_B
    float* sq_a   = (float*)(bsum + SCAN_B);               // N_ENT*9
    float* sq_b   = sq_a + (size_t)N_ENT * NREL9;          // N_ENT*9

    float* out_ent = (float*)d_out;
    float* out_usr = out_ent + (size_t)N_ENT * CDIM;

    // ---- CSR build (indices are hop-invariant: once per call) ----
    k_zero<<<(NTOT + 255) / 256, 256, 0, stream>>>(cnt, NTOT);
    k_hist<<<(NE + 255) / 256, 256, 0, stream>>>(head, inter_cols, inter_rows, cnt);
    k_bsum<<<SCAN_B, 1024, 0, stream>>>(cnt, bsum);
    k_scan_small<<<1, 512, 0, stream>>>(bsum);
    k_scan_apply<<<SCAN_B, 1024, 0, stream>>>(cnt, bsum, start, cursor);
    k_scatter<<<(NE + 255) / 256, 256, 0, stream>>>(
        head, tailp, etype, inter_rows, inter_cols, inter_vals,
        cursor, pk_h, rc, cv);

    const int EG = N_ENT / 4;   // 4 waves per 256-thread block, exact
    const int UG = N_USR / 4;

    // ---- hop 1: read inputs; write ent_a/usr_a/sq_b; out = input + y1 ----
    k_sqnorm<<<EG, 256, 0, stream>>>(entity_emb, wt, sq_a);
    k_user<true, false><<<UG, 256, 0, stream>>>(
        entity_emb, user_emb, start, cv, usr_a, out_usr);
    k_entity<true, false><<<EG, 256, 0, stream>>>(
        entity_emb, user_emb, wt, start, pk_h, sq_a, rc, ent_a, sq_b, out_ent);

    // ---- hop 2: read ent_a/usr_a/sq_b; out += y2 ----
    k_user<false, true><<<UG, 256, 0, stream>>>(
        ent_a, nullptr, start, cv, nullptr, out_usr);
    k_entity<false, true><<<EG, 256, 0, stream>>>(
        ent_a, usr_a, wt, start, pk_h, sq_b, rc, nullptr, nullptr, out_ent);
}